// Round 10
// baseline (46.886 us; speedup 1.0000x reference)
//
#include <hip/hip_runtime.h>

// ---------------------------------------------------------------------------
// tNet: einsum chain is linear in x.
// Kernel 1 (grid 512): blocks 0..255 build 4 rows each of W_eff (1024x1024,
//   bf16) + init out=fc2_b; blocks 256..511 convert X f32->bf16 (Xb).
// Kernel 2 (grid 16x16, 512 thr): LDS-FREE MFMA GEMM. Xb+Wb = 4 MB is
//   L2-resident (per-XCD working set ~2.25 MB); every MFMA fragment is read
//   directly from global/L2 (coalesced 16x64B lines), no staging, no
//   barriers in the K-loop. Wave w: z-band (w>>1)*16, o-half (w&1)*32;
//   acc[2] = two 16x16x32 frags; 32 K-steps x {1 A-load, 2 B-loads, 2 MFMA}.
//   Epilogue: relu H-tile -> LDS, fused fc2 partials -> atomicAdd(out).
//   t5[z,d,r,t] = sum_{a,b,c,e,p,q,s} x[z,a,b,c] u1[a,d,e] b2[e,p,q]
//                                     u2[b,r,p] b1c[q,s] u3[c,t,s]
//   o = d*128+r*16+t ; i = a*128+b*16+c
// ---------------------------------------------------------------------------

using s16x8 = __attribute__((ext_vector_type(8))) short;   // 8 bf16
using f32x4 = __attribute__((ext_vector_type(4))) float;

__device__ inline short f2bf(float f) {
    unsigned u = __builtin_bit_cast(unsigned, f);
    u += 0x7fffu + ((u >> 16) & 1u);          // round-to-nearest-even
    return (short)(u >> 16);
}

// grid 512: blk<256 -> build W rows [blk*4, blk*4+4) + init out
//           blk>=256 -> convert 4096 elements of X to bf16
__global__ __launch_bounds__(256) void k_prep(
    const float* __restrict__ x, const float* __restrict__ u1,
    const float* __restrict__ u2, const float* __restrict__ u3,
    const float* __restrict__ b2, const float* __restrict__ b1c,
    const float* __restrict__ fc2b, short* __restrict__ Wb,
    short* __restrict__ Xb, float* __restrict__ out) {
    const int blk = blockIdx.x;
    const int tid = threadIdx.x;

    if (blk >= 256) {                          // X f32 -> bf16
        const int base = (blk - 256) * 4096 + tid * 16;
#pragma unroll
        for (int h = 0; h < 2; ++h) {
            float4 f0 = *(const float4*)&x[base + h * 8];
            float4 f1 = *(const float4*)&x[base + h * 8 + 4];
            s16x8 v;
            v[0] = f2bf(f0.x); v[1] = f2bf(f0.y);
            v[2] = f2bf(f0.z); v[3] = f2bf(f0.w);
            v[4] = f2bf(f1.x); v[5] = f2bf(f1.y);
            v[6] = f2bf(f1.z); v[7] = f2bf(f1.w);
            *(s16x8*)&Xb[base + h * 8] = v;
        }
        return;
    }

    __shared__ float C2f[4096];
    __shared__ float T1s[2048];
    __shared__ float T2s[64 * 17];
    const int d = blk >> 5;
    const int r = (blk >> 2) & 7;
    const int t0 = (blk & 3) * 4;

    if (tid < 40) {                            // out init: 256*40 = 10240
        int idx = blk * 40 + tid;
        out[idx] = fc2b[idx % 10];
    }
    // C2[e,p,s]
#pragma unroll
    for (int j = 0; j < 16; ++j) {
        int idx = tid + 256 * j;
        int p = (idx >> 4) & 15, s = idx & 15;
        float acc = 0.f;
#pragma unroll
        for (int q = 0; q < 16; ++q)
            acc += b2[j * 256 + p * 16 + q] * b1c[q * 16 + s];
        C2f[idx] = acc;
    }
    __syncthreads();
    // T1[a][p*16+s]  (d fixed)
#pragma unroll
    for (int j = 0; j < 8; ++j) {
        float acc = 0.f;
#pragma unroll
        for (int e = 0; e < 16; ++e)
            acc += u1[(j * 8 + d) * 16 + e] * C2f[e * 256 + tid];
        T1s[j * 256 + tid] = acc;
    }
    __syncthreads();
    // T2[ab][s] (r fixed), stride 17 kills bank conflicts
#pragma unroll
    for (int j = 0; j < 4; ++j) {
        int idx = tid + 256 * j;
        int ab = idx >> 4, s = idx & 15;
        int a = ab >> 3, b = ab & 7;
        float acc = 0.f;
#pragma unroll
        for (int p = 0; p < 16; ++p)
            acc += T1s[a * 256 + p * 16 + s] * u2[(b * 8 + r) * 16 + p];
        T2s[ab * 17 + s] = acc;
    }
    __syncthreads();
    // W rows o = blk*4 + j ; thread covers cols [col0, col0+16)
    {
        const int j = tid >> 6;
        const int t = t0 + j;
        const int col0 = (tid & 63) * 16;
        const int ab = col0 >> 4;
        const float* t2p = &T2s[ab * 17];
        short* wrow = &Wb[(blk * 4 + j) * 1024 + col0];
        s16x8 v0, v1;
#pragma unroll
        for (int c = 0; c < 16; ++c) {
            const float* u3p = &u3[c * 256 + t * 16];
            float acc = 0.f;
#pragma unroll
            for (int s = 0; s < 16; ++s) acc += t2p[s] * u3p[s];
            short bf = f2bf(acc);
            if (c < 8) v0[c] = bf; else v1[c - 8] = bf;
        }
        *(s16x8*)(wrow) = v0;
        *(s16x8*)(wrow + 8) = v1;
    }
}

// ---------------------------------------------------------------------------
// LDS-free MFMA GEMM + fused fc2. Grid (16,16), 512 threads = 8 waves.
// Wave w: z-band = (w>>1)*16, o-half = (w&1)*32. All operands straight from
// L2; no K-loop barriers; LDS only for the epilogue H-tile + fc2 weights.
// ---------------------------------------------------------------------------
__global__ __launch_bounds__(512) void k_gemm(
    const short* __restrict__ Xb, const short* __restrict__ Wb,
    const float* __restrict__ bias, const float* __restrict__ W2,
    float* __restrict__ out) {
    __shared__ float Ht[64][66];               // 16896 B (66: ~2-4-way max)
    __shared__ float W2s[10][64];
    const int tid = threadIdx.x;
    const int lane = tid & 63;
    const int wid = tid >> 6;                  // 0..7
    const int band = wid >> 1;                 // z band (16 rows)
    const int half = wid & 1;                  // o half (32 cols)
    const int o0 = blockIdx.x * 64, z0 = blockIdx.y * 64;
    const int lr = lane & 15, lk = lane >> 4;

    if (tid < 160) {                           // stage fc2_w tile [10][64]
        const int j = tid >> 4, c = (tid & 15) * 4;
        *(float4*)&W2s[j][c] = *(const float4*)&W2[j * 1024 + o0 + c];
    }

    const short* ap  = &Xb[(z0 + band * 16 + lr) * 1024 + lk * 8];
    const short* b0p = &Wb[(o0 + half * 32 + lr) * 1024 + lk * 8];
    const short* b1p = b0p + 16 * 1024;

    f32x4 acc[2] = {};
    for (int kt = 0; kt < 4; ++kt) {
#pragma unroll
        for (int k8 = 0; k8 < 8; ++k8) {
            const int off = kt * 256 + k8 * 32;
            s16x8 av = *(const s16x8*)(ap + off);
            s16x8 b0 = *(const s16x8*)(b0p + off);
            s16x8 b1 = *(const s16x8*)(b1p + off);
            acc[0] = __builtin_amdgcn_mfma_f32_16x16x32_bf16(av, b0, acc[0], 0, 0, 0);
            acc[1] = __builtin_amdgcn_mfma_f32_16x16x32_bf16(av, b1, acc[1], 0, 0, 0);
        }
    }

    // ---- epilogue: relu H-tile into LDS. D layout: col=lane&15, row=lk*4+j
#pragma unroll
    for (int n = 0; n < 2; ++n) {
        const int oc = half * 32 + n * 16 + lr;
        const float bv = bias[o0 + oc];
#pragma unroll
        for (int j = 0; j < 4; ++j)
            Ht[band * 16 + lk * 4 + j][oc] = fmaxf(acc[n][j] + bv, 0.f);
    }
    __syncthreads();

    // ---- fused fc2: 8 threads per z-row over 64 cols -> atomicAdd(out)
    const int zr = tid >> 3, q8 = tid & 7;
    float part[10];
#pragma unroll
    for (int jj = 0; jj < 10; ++jj) part[jj] = 0.f;
#pragma unroll
    for (int cc = 0; cc < 8; ++cc) {
        const int cl = q8 + 8 * cc;
        const float hv = Ht[zr][cl];
#pragma unroll
        for (int jj = 0; jj < 10; ++jj) part[jj] += hv * W2s[jj][cl];
    }
#pragma unroll
    for (int jj = 0; jj < 10; ++jj) {
        float p = part[jj];
        p += __shfl_xor(p, 1);
        p += __shfl_xor(p, 2);
        p += __shfl_xor(p, 4);
        if (q8 == 0) atomicAdd(&out[(z0 + zr) * 10 + jj], p);
    }
}

extern "C" void kernel_launch(void* const* d_in, const int* in_sizes, int n_in,
                              void* d_out, int out_size, void* d_ws, size_t ws_size,
                              hipStream_t stream) {
    const float* x     = (const float*)d_in[0];
    const float* u1    = (const float*)d_in[1];
    const float* u2    = (const float*)d_in[2];
    const float* u3    = (const float*)d_in[3];
    const float* b2    = (const float*)d_in[4];
    const float* b1c   = (const float*)d_in[5];
    const float* bias1 = (const float*)d_in[6];
    const float* fc2w  = (const float*)d_in[7];
    const float* fc2b  = (const float*)d_in[8];
    float* out = (float*)d_out;

    short* Wb = (short*)d_ws;                                  // 2 MB bf16
    short* Xb = (short*)((char*)d_ws + 2u * 1024u * 1024u);    // 2 MB bf16

    k_prep<<<512, 256, 0, stream>>>(x, u1, u2, u3, b2, b1c, fc2b, Wb, Xb, out);
    k_gemm<<<dim3(16, 16), 512, 0, stream>>>(Xb, Wb, bias1, fc2w, out);
}

// Round 11
// 37.977 us; speedup vs baseline: 1.2346x; 1.2346x over previous
//
#include <hip/hip_runtime.h>

// ---------------------------------------------------------------------------
// tNet: einsum chain is linear in x => H = relu(X @ W_eff^T + bias1),
// out = H @ fc2_w^T + fc2_b.
//   t5[z,d,r,t] = sum_{a,b,c,e,p,q,s} x[z,a,b,c] u1[a,d,e] b2[e,p,q]
//                                     u2[b,r,p] b1c[q,s] u3[c,t,s]
//   o = d*128+r*16+t ; i = a*128+b*16+c
// k_main: grid (32 o-tiles x 8 z-tiles), 512 thr, 84.7KB LDS. Per block:
//   phase A (5 barriers total, none in K-loop):
//     C2[e,p,s]=sum_q b2*b1c ; T1[a,p,s]=sum_e u1[a*8+d]*C2 (d fixed);
//     T2[r2,ab,s]=sum_p T1*u2 (2 r-values); then build ALL 32 W rows x 1024
//     cols ONCE into LDS (b128 broadcast T2 reads + u3 regs, 64 out/thread).
//   K-loop (8 chunks x 4 ks): X f32 direct global->regs (wave-exclusive
//     rows, next-chunk prefetch), f2bf in-reg, B-frags from W-LDS
//     (stride 1032 shorts -> <=2-way), 2 MFMA/ks. ZERO barriers.
//   epilogue: relu H-tile -> LDS, fc2 partials -> P (plain stores).
// k_reduce: out[z][j] = fc2_b[j] + sum_ob P[ob][z][j].
// ---------------------------------------------------------------------------

using s16x8 = __attribute__((ext_vector_type(8))) short;   // 8 bf16
using f32x4 = __attribute__((ext_vector_type(4))) float;

__device__ inline short f2bf(float f) {
    unsigned u = __builtin_bit_cast(unsigned, f);
    u += 0x7fffu + ((u >> 16) & 1u);          // round-to-nearest-even
    return (short)(u >> 16);
}

#define W_STRIDE 1032                          // shorts; 2064B row = 16B-aligned, %32words=4
#define OFF_HT   66048                         // W[32][1032]*2
#define OFF_W2   83456                         // + Ht[128][34]*4 (T2 aliases Ht)
#define SMEM_SZ  84736                         // + W2s[10][32]*4

__global__ __launch_bounds__(512) void k_main(
    const float* __restrict__ x, const float* __restrict__ u1,
    const float* __restrict__ u2, const float* __restrict__ u3,
    const float* __restrict__ b2, const float* __restrict__ b1c,
    const float* __restrict__ bias1, const float* __restrict__ fc2w,
    float* __restrict__ P) {
    __shared__ char smem[SMEM_SZ];
    short* Wl  = (short*)smem;                 // [32][1032] bf16 W tile
    float* C2f = (float*)smem;                 // 4096 f32 (phase-A alias)
    float* T1s = (float*)(smem + 16384);       // 2048 f32 (phase-A alias)
    float* T2  = (float*)(smem + OFF_HT);      // 2048 f32 (aliases Ht)
    float* Ht  = (float*)(smem + OFF_HT);      // [128][34] f32 (epilogue)
    float* W2s = (float*)(smem + OFF_W2);      // [10][32] f32

    const int tid = threadIdx.x;
    const int obk = blockIdx.x;                // 0..31: o-rows [obk*32, +32)
    const int zbk = blockIdx.y;                // 0..7 : z-rows [zbk*128, +128)
    const int o0 = obk * 32;
    const int z0 = zbk * 128;
    const int d = obk >> 2;

    // per-thread u3 slice (c,t fixed), 16 regs
    const int c_u = tid & 15, t_u = (tid >> 4) & 15, half = tid >> 8;
    float u3r[16];
    {
        const float4* up = (const float4*)&u3[c_u * 256 + t_u * 16];
#pragma unroll
        for (int q = 0; q < 4; ++q) {
            float4 v = up[q];
            u3r[q * 4 + 0] = v.x; u3r[q * 4 + 1] = v.y;
            u3r[q * 4 + 2] = v.z; u3r[q * 4 + 3] = v.w;
        }
    }
    if (tid < 320) W2s[tid] = fc2w[(tid >> 5) * 1024 + o0 + (tid & 31)];

    // ---- phase A: C2 -> T1 -> T2 ----
#pragma unroll
    for (int j = 0; j < 8; ++j) {              // C2: 4096 = 512*8
        int idx = tid + 512 * j;
        int e = idx >> 8, p = (idx >> 4) & 15, s = idx & 15;
        float acc = 0.f;
#pragma unroll
        for (int q = 0; q < 16; ++q)
            acc += b2[e * 256 + p * 16 + q] * b1c[q * 16 + s];
        C2f[idx] = acc;
    }
    __syncthreads();
#pragma unroll
    for (int j = 0; j < 4; ++j) {              // T1: 2048 = 512*4, [a][p*16+s]
        int idx = tid + 512 * j;
        int a = idx >> 8, ps = idx & 255;
        float acc = 0.f;
#pragma unroll
        for (int e = 0; e < 16; ++e)
            acc += u1[(a * 8 + d) * 16 + e] * C2f[e * 256 + ps];
        T1s[idx] = acc;
    }
    __syncthreads();
#pragma unroll
    for (int j = 0; j < 4; ++j) {              // T2: 2048 = 512*4, [r2][ab][s]
        int idx = tid + 512 * j;
        int r2 = idx >> 10, ab = (idx >> 4) & 63, s = idx & 15;
        int a = ab >> 3, b = ab & 7;
        int rf = (obk * 2 + r2) & 7;
        float acc = 0.f;
#pragma unroll
        for (int p = 0; p < 16; ++p)
            acc += T1s[a * 256 + p * 16 + s] * u2[(b * 8 + rf) * 16 + p];
        T2[idx] = acc;
    }
    __syncthreads();                           // C2f/T1s dead; W region free

    // ---- build all 32 W rows x 1024 cols into LDS (once) ----
    // thread covers (c_u, t_u, half): 2 r2 x 8 a x 4 b-half = 64 outputs
#pragma unroll
    for (int r2 = 0; r2 < 2; ++r2)
        for (int a = 0; a < 8; ++a)
#pragma unroll
            for (int bi = 0; bi < 4; ++bi) {
                const int b = half * 4 + bi;
                const f32x4* t2p = (const f32x4*)&T2[((r2 * 8 + a) * 8 + b) * 16];
                float acw = 0.f;
#pragma unroll
                for (int q4 = 0; q4 < 4; ++q4) {      // b128 broadcast reads
                    f32x4 tv = t2p[q4];
                    acw += tv[0] * u3r[q4 * 4 + 0] + tv[1] * u3r[q4 * 4 + 1]
                         + tv[2] * u3r[q4 * 4 + 2] + tv[3] * u3r[q4 * 4 + 3];
                }
                Wl[(r2 * 16 + t_u) * W_STRIDE + a * 128 + b * 16 + c_u] = f2bf(acw);
            }
    __syncthreads();                           // W ready; T2 dead (Ht free)

    // ---- K-loop: zero barriers. wave = 16 z-rows x all 32 o-cols ----
    const int lane = tid & 63;
    const int wid = tid >> 6;                  // 0..7
    const int lr = lane & 15, lk = lane >> 4;
    const float* xp = &x[(z0 + wid * 16 + lr) * 1024 + lk * 8];

    f32x4 acc[2] = {};
    float4 ax[8];
#pragma unroll
    for (int q = 0; q < 8; ++q)
        ax[q] = *(const float4*)(xp + (q >> 1) * 32 + (q & 1) * 4);

    for (int ch = 0; ch < 8; ++ch) {
        float4 nx[8];
        if (ch < 7) {                          // prefetch next chunk
#pragma unroll
            for (int q = 0; q < 8; ++q)
                nx[q] = *(const float4*)(xp + (ch + 1) * 128 + (q >> 1) * 32 + (q & 1) * 4);
        }
#pragma unroll
        for (int ks = 0; ks < 4; ++ks) {
            float4 lo = ax[ks * 2], hi = ax[ks * 2 + 1];
            s16x8 av;
            av[0] = f2bf(lo.x); av[1] = f2bf(lo.y);
            av[2] = f2bf(lo.z); av[3] = f2bf(lo.w);
            av[4] = f2bf(hi.x); av[5] = f2bf(hi.y);
            av[6] = f2bf(hi.z); av[7] = f2bf(hi.w);
            const int kb = ch * 128 + ks * 32 + lk * 8;
            s16x8 b0 = *(const s16x8*)&Wl[(lr) * W_STRIDE + kb];
            s16x8 b1 = *(const s16x8*)&Wl[(16 + lr) * W_STRIDE + kb];
            acc[0] = __builtin_amdgcn_mfma_f32_16x16x32_bf16(av, b0, acc[0], 0, 0, 0);
            acc[1] = __builtin_amdgcn_mfma_f32_16x16x32_bf16(av, b1, acc[1], 0, 0, 0);
        }
        if (ch < 7) {
#pragma unroll
            for (int q = 0; q < 8; ++q) ax[q] = nx[q];
        }
    }

    // ---- epilogue: relu H-tile -> Ht (T2 region dead, no barrier needed)
#pragma unroll
    for (int n = 0; n < 2; ++n) {
        const int oc = n * 16 + lr;
        const float bv = bias1[o0 + oc];
#pragma unroll
        for (int j = 0; j < 4; ++j)
            Ht[(wid * 16 + lk * 4 + j) * 34 + oc] = fmaxf(acc[n][j] + bv, 0.f);
    }
    __syncthreads();

    // ---- fc2 partials: 4 threads per z-row over 32 cols -> P (plain store)
    const int zr = tid >> 2, q = tid & 3;
    float part[10];
#pragma unroll
    for (int jj = 0; jj < 10; ++jj) part[jj] = 0.f;
#pragma unroll
    for (int cc = 0; cc < 8; ++cc) {
        const int cl = q + 4 * cc;
        const float hv = Ht[zr * 34 + cl];
#pragma unroll
        for (int jj = 0; jj < 10; ++jj) part[jj] += hv * W2s[jj * 32 + cl];
    }
#pragma unroll
    for (int jj = 0; jj < 10; ++jj) {
        float p = part[jj];
        p += __shfl_xor(p, 1);
        p += __shfl_xor(p, 2);
        if (q == 0) P[(obk * 1024 + z0 + zr) * 10 + jj] = p;
    }
}

__global__ __launch_bounds__(256) void k_reduce(
    const float* __restrict__ P, const float* __restrict__ fc2b,
    float* __restrict__ out) {
    const int idx = blockIdx.x * 256 + threadIdx.x;    // 10240
    const int j = idx - (idx / 10) * 10;
    float acc = fc2b[j];
#pragma unroll
    for (int ob = 0; ob < 32; ++ob) acc += P[ob * 10240 + idx];
    out[idx] = acc;
}

extern "C" void kernel_launch(void* const* d_in, const int* in_sizes, int n_in,
                              void* d_out, int out_size, void* d_ws, size_t ws_size,
                              hipStream_t stream) {
    const float* x     = (const float*)d_in[0];
    const float* u1    = (const float*)d_in[1];
    const float* u2    = (const float*)d_in[2];
    const float* u3    = (const float*)d_in[3];
    const float* b2    = (const float*)d_in[4];
    const float* b1c   = (const float*)d_in[5];
    const float* bias1 = (const float*)d_in[6];
    const float* fc2w  = (const float*)d_in[7];
    const float* fc2b  = (const float*)d_in[8];
    float* out = (float*)d_out;
    float* P = (float*)d_ws;                   // [32][1024][10] f32 = 1.31 MB

    k_main<<<dim3(32, 8), 512, 0, stream>>>(x, u1, u2, u3, b2, b1c, bias1,
                                            fc2w, P);
    k_reduce<<<40, 256, 0, stream>>>(P, fc2b, out);
}

// Round 12
// 31.776 us; speedup vs baseline: 1.4755x; 1.1951x over previous
//
#include <hip/hip_runtime.h>

// ---------------------------------------------------------------------------
// tNet: einsum chain is linear in x.
// k_prep (grid 512): blocks 0..255 build 4 rows each of W_eff (1024x1024,
//   bf16); blocks 256..511 convert X f32->bf16 (Xb).
// k_gemm (grid 16x16x4 = 1024 blocks = 4 blocks/CU = 4 waves/SIMD):
//   SPLIT-K MFMA GEMM. Block (ox,zy,kz) computes the 64x64 tile's partial
//   over K-slice [kz*256, kz*256+256) (2 x BK=128 LDS iterations, proven
//   R3/R5 staging+fragment code) and stores f32 partials to PH[kz][z][o].
// k_out (grid 256): H[z][o] = relu(sum_kz PH + bias1); out = H@fc2_w^T+fc2_b,
//   one wave per z-row, no atomics.
//   t5[z,d,r,t] = sum_{a,b,c,e,p,q,s} x[z,a,b,c] u1[a,d,e] b2[e,p,q]
//                                     u2[b,r,p] b1c[q,s] u3[c,t,s]
//   o = d*128+r*16+t ; i = a*128+b*16+c
// ---------------------------------------------------------------------------

using s16x8 = __attribute__((ext_vector_type(8))) short;   // 8 bf16
using f32x4 = __attribute__((ext_vector_type(4))) float;

__device__ inline short f2bf(float f) {
    unsigned u = __builtin_bit_cast(unsigned, f);
    u += 0x7fffu + ((u >> 16) & 1u);          // round-to-nearest-even
    return (short)(u >> 16);
}

// grid 512: blk<256 -> build W rows [blk*4, blk*4+4); blk>=256 -> X->bf16
__global__ __launch_bounds__(256) void k_prep(
    const float* __restrict__ x, const float* __restrict__ u1,
    const float* __restrict__ u2, const float* __restrict__ u3,
    const float* __restrict__ b2, const float* __restrict__ b1c,
    short* __restrict__ Wb, short* __restrict__ Xb) {
    const int blk = blockIdx.x;
    const int tid = threadIdx.x;

    if (blk >= 256) {                          // X f32 -> bf16
        const int base = (blk - 256) * 4096 + tid * 16;
#pragma unroll
        for (int h = 0; h < 2; ++h) {
            float4 f0 = *(const float4*)&x[base + h * 8];
            float4 f1 = *(const float4*)&x[base + h * 8 + 4];
            s16x8 v;
            v[0] = f2bf(f0.x); v[1] = f2bf(f0.y);
            v[2] = f2bf(f0.z); v[3] = f2bf(f0.w);
            v[4] = f2bf(f1.x); v[5] = f2bf(f1.y);
            v[6] = f2bf(f1.z); v[7] = f2bf(f1.w);
            *(s16x8*)&Xb[base + h * 8] = v;
        }
        return;
    }

    __shared__ float C2f[4096];
    __shared__ float T1s[2048];
    __shared__ float T2s[64 * 17];
    const int d = blk >> 5;
    const int r = (blk >> 2) & 7;
    const int t0 = (blk & 3) * 4;

    // C2[e,p,s]
#pragma unroll
    for (int j = 0; j < 16; ++j) {
        int idx = tid + 256 * j;
        int p = (idx >> 4) & 15, s = idx & 15;
        float acc = 0.f;
#pragma unroll
        for (int q = 0; q < 16; ++q)
            acc += b2[j * 256 + p * 16 + q] * b1c[q * 16 + s];
        C2f[idx] = acc;
    }
    __syncthreads();
    // T1[a][p*16+s]  (d fixed)
#pragma unroll
    for (int j = 0; j < 8; ++j) {
        float acc = 0.f;
#pragma unroll
        for (int e = 0; e < 16; ++e)
            acc += u1[(j * 8 + d) * 16 + e] * C2f[e * 256 + tid];
        T1s[j * 256 + tid] = acc;
    }
    __syncthreads();
    // T2[ab][s] (r fixed), stride 17 kills bank conflicts
#pragma unroll
    for (int j = 0; j < 4; ++j) {
        int idx = tid + 256 * j;
        int ab = idx >> 4, s = idx & 15;
        int a = ab >> 3, b = ab & 7;
        float acc = 0.f;
#pragma unroll
        for (int p = 0; p < 16; ++p)
            acc += T1s[a * 256 + p * 16 + s] * u2[(b * 8 + r) * 16 + p];
        T2s[ab * 17 + s] = acc;
    }
    __syncthreads();
    // W rows o = blk*4 + j ; thread covers cols [col0, col0+16)
    {
        const int j = tid >> 6;
        const int t = t0 + j;
        const int col0 = (tid & 63) * 16;
        const int ab = col0 >> 4;
        const float* t2p = &T2s[ab * 17];
        short* wrow = &Wb[(blk * 4 + j) * 1024 + col0];
        s16x8 v0, v1;
#pragma unroll
        for (int c = 0; c < 16; ++c) {
            const float* u3p = &u3[c * 256 + t * 16];
            float acc = 0.f;
#pragma unroll
            for (int s = 0; s < 16; ++s) acc += t2p[s] * u3p[s];
            short bf = f2bf(acc);
            if (c < 8) v0[c] = bf; else v1[c - 8] = bf;
        }
        *(s16x8*)(wrow) = v0;
        *(s16x8*)(wrow + 8) = v1;
    }
}

// ---------------------------------------------------------------------------
// Split-K MFMA GEMM. Grid (16 o, 16 z, 4 kz); 256 thr = 4 waves (2x2);
// wave tile 32x32 via 2x2 16x16x32 frags; BK=128, 2 iterations per block.
// LDS 34.8 KB -> 4 blocks/CU -> 4 waves/SIMD (the TLP R5 lacked).
// ---------------------------------------------------------------------------
#define LDK 136

__global__ __launch_bounds__(256) void k_gemm(
    const short* __restrict__ Xb, const short* __restrict__ Wb,
    float* __restrict__ PH) {
    __shared__ short As[64][LDK];              // 17408 B
    __shared__ short Bs[64][LDK];              // 17408 B
    const int tid = threadIdx.x;
    const int lane = tid & 63;
    const int w = tid >> 6, wr = w >> 1, wc = w & 1;
    const int o0 = blockIdx.x * 64, z0 = blockIdx.y * 64, kz = blockIdx.z;
    const int srow = tid >> 2;                 // 0..63, 4 thr/row
    const int sc = (tid & 3) * 16;             // halves at +0,+64

    const short* xp = &Xb[(z0 + srow) * 1024 + kz * 256 + sc];
    const short* wp = &Wb[(o0 + srow) * 1024 + kz * 256 + sc];

    f32x4 acc[2][2] = {};
    s16x8 ax[4], bx[4];                        // [h*2+q]

#pragma unroll
    for (int h = 0; h < 2; ++h)
#pragma unroll
        for (int q = 0; q < 2; ++q) {
            ax[h * 2 + q] = *(const s16x8*)(xp + h * 64 + q * 8);
            bx[h * 2 + q] = *(const s16x8*)(wp + h * 64 + q * 8);
        }

#pragma unroll
    for (int it = 0; it < 2; ++it) {
#pragma unroll
        for (int h = 0; h < 2; ++h)
#pragma unroll
            for (int q = 0; q < 2; ++q) {
                *(s16x8*)&As[srow][sc + h * 64 + q * 8] = ax[h * 2 + q];
                *(s16x8*)&Bs[srow][sc + h * 64 + q * 8] = bx[h * 2 + q];
            }
        __syncthreads();
        if (it == 0) {                         // prefetch second half-slice
#pragma unroll
            for (int h = 0; h < 2; ++h)
#pragma unroll
                for (int q = 0; q < 2; ++q) {
                    ax[h * 2 + q] = *(const s16x8*)(xp + 128 + h * 64 + q * 8);
                    bx[h * 2 + q] = *(const s16x8*)(wp + 128 + h * 64 + q * 8);
                }
        }
#pragma unroll
        for (int ks = 0; ks < 4; ++ks) {
            const int kb = ks * 32 + (lane >> 4) * 8;
            s16x8 a0 = *(const s16x8*)&As[wr * 32 + (lane & 15)][kb];
            s16x8 a1 = *(const s16x8*)&As[wr * 32 + 16 + (lane & 15)][kb];
            s16x8 b0 = *(const s16x8*)&Bs[wc * 32 + (lane & 15)][kb];
            s16x8 b1 = *(const s16x8*)&Bs[wc * 32 + 16 + (lane & 15)][kb];
            acc[0][0] = __builtin_amdgcn_mfma_f32_16x16x32_bf16(a0, b0, acc[0][0], 0, 0, 0);
            acc[0][1] = __builtin_amdgcn_mfma_f32_16x16x32_bf16(a0, b1, acc[0][1], 0, 0, 0);
            acc[1][0] = __builtin_amdgcn_mfma_f32_16x16x32_bf16(a1, b0, acc[1][0], 0, 0, 0);
            acc[1][1] = __builtin_amdgcn_mfma_f32_16x16x32_bf16(a1, b1, acc[1][1], 0, 0, 0);
        }
        __syncthreads();
    }

    // partial C store: D layout col=lane&15, row=(lane>>4)*4+j
    float* ph = &PH[(unsigned)kz * 1048576u];
#pragma unroll
    for (int m = 0; m < 2; ++m)
#pragma unroll
        for (int n = 0; n < 2; ++n) {
            const int row = z0 + wr * 32 + m * 16 + (lane >> 4) * 4;
            const int col = o0 + wc * 32 + n * 16 + (lane & 15);
#pragma unroll
            for (int j = 0; j < 4; ++j)
                ph[(row + j) * 1024 + col] = acc[m][n][j];
        }
}

// ---------------------------------------------------------------------------
// k_out: H = relu(sum of 4 PH slices + bias1); out = H @ fc2_w^T + fc2_b.
// 256 blocks x 256 thr; one wave per z-row (4 rows/block). No atomics.
// ---------------------------------------------------------------------------
__global__ __launch_bounds__(256) void k_out(
    const float* __restrict__ PH, const float* __restrict__ bias1,
    const float* __restrict__ W2, const float* __restrict__ fc2b,
    float* __restrict__ out) {
    __shared__ float W2s[10][1024];            // 40 KB
    const int tid = threadIdx.x;
#pragma unroll
    for (int i = 0; i < 10; ++i) {             // stage all of fc2_w
        const int idx = tid + 256 * i;         // 2560 float4
        ((float4*)W2s)[idx] = ((const float4*)W2)[idx];
    }
    __syncthreads();

    const int wid = tid >> 6, lane = tid & 63;
    const int z = blockIdx.x * 4 + wid;
    float part[10];
#pragma unroll
    for (int j = 0; j < 10; ++j) part[j] = 0.f;
#pragma unroll
    for (int i = 0; i < 16; ++i) {
        const int col = lane + 64 * i;
        float h = PH[z * 1024 + col] + PH[1048576 + z * 1024 + col]
                + PH[2097152 + z * 1024 + col] + PH[3145728 + z * 1024 + col];
        h = fmaxf(h + bias1[col], 0.f);
#pragma unroll
        for (int j = 0; j < 10; ++j) part[j] += h * W2s[j][col];
    }
#pragma unroll
    for (int j = 0; j < 10; ++j) {
#pragma unroll
        for (int off = 32; off > 0; off >>= 1) part[j] += __shfl_xor(part[j], off);
    }
    if (lane == 0) {
#pragma unroll
        for (int j = 0; j < 10; ++j) out[z * 10 + j] = part[j] + fc2b[j];
    }
}

extern "C" void kernel_launch(void* const* d_in, const int* in_sizes, int n_in,
                              void* d_out, int out_size, void* d_ws, size_t ws_size,
                              hipStream_t stream) {
    const float* x     = (const float*)d_in[0];
    const float* u1    = (const float*)d_in[1];
    const float* u2    = (const float*)d_in[2];
    const float* u3    = (const float*)d_in[3];
    const float* b2    = (const float*)d_in[4];
    const float* b1c   = (const float*)d_in[5];
    const float* bias1 = (const float*)d_in[6];
    const float* fc2w  = (const float*)d_in[7];
    const float* fc2b  = (const float*)d_in[8];
    float* out = (float*)d_out;

    short* Wb = (short*)d_ws;                                  // 2 MB bf16
    short* Xb = (short*)((char*)d_ws + 2u * 1024u * 1024u);    // 2 MB bf16
    float* PH = (float*)((char*)d_ws + 4u * 1024u * 1024u);    // 16 MB f32

    k_prep<<<512, 256, 0, stream>>>(x, u1, u2, u3, b2, b1c, Wb, Xb);
    k_gemm<<<dim3(16, 16, 4), 256, 0, stream>>>(Xb, Wb, PH);
    k_out<<<256, 256, 0, stream>>>(PH, bias1, fc2w, fc2b, out);
}

// Round 13
// 29.034 us; speedup vs baseline: 1.6148x; 1.0944x over previous
//
#include <hip/hip_runtime.h>

// ---------------------------------------------------------------------------
// tNet: einsum chain is linear in x.
// k_prep (grid 512): blocks 0..255 build 4 rows each of W_eff (1024x1024,
//   bf16); blocks 256..511 convert X f32->bf16 (Xb).
//   R13: ALL small tensors staged to LDS/regs with coalesced loads first;
//   compute loops touch only LDS (broadcast or conflict-free) -- the R5/R12
//   version did ~700 latency-exposed scalar GLOBAL loads per thread inside
//   the FMA chains (u3/b2/u1/u2), which was ~25 us of the 31.6 plateau.
// k_gemm (grid 16x16x4, split-K, 4 blocks/CU): unchanged from R12.
// k_out (grid 256): H = relu(sum_kz PH + bias1); out = H@fc2_w^T + fc2_b.
//   t5[z,d,r,t] = sum_{a,b,c,e,p,q,s} x[z,a,b,c] u1[a,d,e] b2[e,p,q]
//                                     u2[b,r,p] b1c[q,s] u3[c,t,s]
//   o = d*128+r*16+t ; i = a*128+b*16+c
// ---------------------------------------------------------------------------

using s16x8 = __attribute__((ext_vector_type(8))) short;   // 8 bf16
using f32x4 = __attribute__((ext_vector_type(4))) float;

__device__ inline short f2bf(float f) {
    unsigned u = __builtin_bit_cast(unsigned, f);
    u += 0x7fffu + ((u >> 16) & 1u);          // round-to-nearest-even
    return (short)(u >> 16);
}

// grid 512: blk<256 -> build W rows [blk*4, blk*4+4); blk>=256 -> X->bf16
__global__ __launch_bounds__(256) void k_prep(
    const float* __restrict__ x, const float* __restrict__ u1,
    const float* __restrict__ u2, const float* __restrict__ u3,
    const float* __restrict__ b2, const float* __restrict__ b1c,
    short* __restrict__ Wb, short* __restrict__ Xb) {
    const int blk = blockIdx.x;
    const int tid = threadIdx.x;

    if (blk >= 256) {                          // X f32 -> bf16
        const int base = (blk - 256) * 4096 + tid * 16;
#pragma unroll
        for (int h = 0; h < 2; ++h) {
            float4 f0 = *(const float4*)&x[base + h * 8];
            float4 f1 = *(const float4*)&x[base + h * 8 + 4];
            s16x8 v;
            v[0] = f2bf(f0.x); v[1] = f2bf(f0.y);
            v[2] = f2bf(f0.z); v[3] = f2bf(f0.w);
            v[4] = f2bf(f1.x); v[5] = f2bf(f1.y);
            v[6] = f2bf(f1.z); v[7] = f2bf(f1.w);
            *(s16x8*)&Xb[base + h * 8] = v;
        }
        return;
    }

    __shared__ float b1s[256];
    __shared__ float u1s[128];                 // u1 d-slice [a][e]
    __shared__ float u2s[64 * 17];             // [br][17] padded
    __shared__ float u3s[4096];                // full u3, linear
    __shared__ float C2t[256 * 17];            // [ep][17] padded
    __shared__ float T1s[2048];                // [a][ps]
    __shared__ float T2s[64 * 17];             // [ab][17] padded
    const int d = blk >> 5;
    const int r = (blk >> 2) & 7;
    const int t0 = (blk & 3) * 4;

    // ---- stage all small tensors (coalesced) ----
    b1s[tid] = b1c[tid];
    {
        float4* dst = (float4*)u3s;
        const float4* src = (const float4*)u3;
#pragma unroll
        for (int q = 0; q < 4; ++q) dst[tid + 256 * q] = src[tid + 256 * q];
    }
    if (tid < 64) {                            // u2 row tid -> padded
        const float4* src = (const float4*)&u2[tid * 16];
#pragma unroll
        for (int q = 0; q < 4; ++q) {
            float4 v = src[q];
            u2s[tid * 17 + q * 4 + 0] = v.x;
            u2s[tid * 17 + q * 4 + 1] = v.y;
            u2s[tid * 17 + q * 4 + 2] = v.z;
            u2s[tid * 17 + q * 4 + 3] = v.w;
        }
    }
    if (tid < 8) {                             // u1 slice: a = tid
#pragma unroll
        for (int e = 0; e < 16; ++e)
            u1s[tid * 16 + e] = u1[(tid * 8 + d) * 16 + e];
    }
    float b2r[16];                             // b2 row (e,p) = tid
    {
        const float4* src = (const float4*)&b2[tid * 16];
#pragma unroll
        for (int q = 0; q < 4; ++q) {
            float4 v = src[q];
            b2r[q * 4 + 0] = v.x; b2r[q * 4 + 1] = v.y;
            b2r[q * 4 + 2] = v.z; b2r[q * 4 + 3] = v.w;
        }
    }
    __syncthreads();

    // ---- C2: thread owns (e,p)=tid; b1s reads are wave-broadcast ----
    {
        float accs[16] = {};
#pragma unroll
        for (int q = 0; q < 16; ++q) {
            const float bq = b2r[q];
#pragma unroll
            for (int s = 0; s < 16; ++s) accs[s] += bq * b1s[q * 16 + s];
        }
#pragma unroll
        for (int s = 0; s < 16; ++s) C2t[tid * 17 + s] = accs[s];
    }
    __syncthreads();

    // ---- T1[a][ps]: thread owns ps=tid; C2t reads <=2-way ----
    {
        const int p = tid >> 4, s = tid & 15;
#pragma unroll
        for (int a = 0; a < 8; ++a) {
            float acc = 0.f;
#pragma unroll
            for (int e = 0; e < 16; ++e)
                acc += u1s[a * 16 + e] * C2t[(e * 16 + p) * 17 + s];
            T1s[a * 256 + tid] = acc;
        }
    }
    __syncthreads();

    // ---- T2[ab][s] (r fixed): T1s reads broadcast, u2s <=2-way ----
#pragma unroll
    for (int j = 0; j < 4; ++j) {
        int idx = tid + 256 * j;
        int ab = idx >> 4, s = idx & 15;
        int a = ab >> 3, b = ab & 7;
        float acc = 0.f;
#pragma unroll
        for (int p = 0; p < 16; ++p)
            acc += T1s[a * 256 + p * 16 + s] * u2s[(b * 8 + r) * 17 + p];
        T2s[ab * 17 + s] = acc;
    }
    __syncthreads();

    // ---- W rows o = blk*4 + j: u3s reads wave-broadcast, T2s 2-way ----
    {
        const int j = tid >> 6;
        const int t = t0 + j;
        const int col0 = (tid & 63) * 16;
        const int ab = col0 >> 4;
        const float* t2p = &T2s[ab * 17];
        short* wrow = &Wb[(blk * 4 + j) * 1024 + col0];
        s16x8 v0, v1;
#pragma unroll
        for (int c = 0; c < 16; ++c) {
            const float* u3p = &u3s[c * 256 + t * 16];
            float acc = 0.f;
#pragma unroll
            for (int s = 0; s < 16; ++s) acc += t2p[s] * u3p[s];
            short bf = f2bf(acc);
            if (c < 8) v0[c] = bf; else v1[c - 8] = bf;
        }
        *(s16x8*)(wrow) = v0;
        *(s16x8*)(wrow + 8) = v1;
    }
}

// ---------------------------------------------------------------------------
// Split-K MFMA GEMM (unchanged from R12). Grid (16 o, 16 z, 4 kz); 256 thr =
// 4 waves (2x2); wave tile 32x32 via 2x2 16x16x32 frags; BK=128, 2 iters.
// LDS 34.8 KB -> 4 blocks/CU -> 4 waves/SIMD.
// ---------------------------------------------------------------------------
#define LDK 136

__global__ __launch_bounds__(256) void k_gemm(
    const short* __restrict__ Xb, const short* __restrict__ Wb,
    float* __restrict__ PH) {
    __shared__ short As[64][LDK];              // 17408 B
    __shared__ short Bs[64][LDK];              // 17408 B
    const int tid = threadIdx.x;
    const int lane = tid & 63;
    const int w = tid >> 6, wr = w >> 1, wc = w & 1;
    const int o0 = blockIdx.x * 64, z0 = blockIdx.y * 64, kz = blockIdx.z;
    const int srow = tid >> 2;                 // 0..63, 4 thr/row
    const int sc = (tid & 3) * 16;             // halves at +0,+64

    const short* xp = &Xb[(z0 + srow) * 1024 + kz * 256 + sc];
    const short* wp = &Wb[(o0 + srow) * 1024 + kz * 256 + sc];

    f32x4 acc[2][2] = {};
    s16x8 ax[4], bx[4];                        // [h*2+q]

#pragma unroll
    for (int h = 0; h < 2; ++h)
#pragma unroll
        for (int q = 0; q < 2; ++q) {
            ax[h * 2 + q] = *(const s16x8*)(xp + h * 64 + q * 8);
            bx[h * 2 + q] = *(const s16x8*)(wp + h * 64 + q * 8);
        }

#pragma unroll
    for (int it = 0; it < 2; ++it) {
#pragma unroll
        for (int h = 0; h < 2; ++h)
#pragma unroll
            for (int q = 0; q < 2; ++q) {
                *(s16x8*)&As[srow][sc + h * 64 + q * 8] = ax[h * 2 + q];
                *(s16x8*)&Bs[srow][sc + h * 64 + q * 8] = bx[h * 2 + q];
            }
        __syncthreads();
        if (it == 0) {                         // prefetch second half-slice
#pragma unroll
            for (int h = 0; h < 2; ++h)
#pragma unroll
                for (int q = 0; q < 2; ++q) {
                    ax[h * 2 + q] = *(const s16x8*)(xp + 128 + h * 64 + q * 8);
                    bx[h * 2 + q] = *(const s16x8*)(wp + 128 + h * 64 + q * 8);
                }
        }
#pragma unroll
        for (int ks = 0; ks < 4; ++ks) {
            const int kb = ks * 32 + (lane >> 4) * 8;
            s16x8 a0 = *(const s16x8*)&As[wr * 32 + (lane & 15)][kb];
            s16x8 a1 = *(const s16x8*)&As[wr * 32 + 16 + (lane & 15)][kb];
            s16x8 b0 = *(const s16x8*)&Bs[wc * 32 + (lane & 15)][kb];
            s16x8 b1 = *(const s16x8*)&Bs[wc * 32 + 16 + (lane & 15)][kb];
            acc[0][0] = __builtin_amdgcn_mfma_f32_16x16x32_bf16(a0, b0, acc[0][0], 0, 0, 0);
            acc[0][1] = __builtin_amdgcn_mfma_f32_16x16x32_bf16(a0, b1, acc[0][1], 0, 0, 0);
            acc[1][0] = __builtin_amdgcn_mfma_f32_16x16x32_bf16(a1, b0, acc[1][0], 0, 0, 0);
            acc[1][1] = __builtin_amdgcn_mfma_f32_16x16x32_bf16(a1, b1, acc[1][1], 0, 0, 0);
        }
        __syncthreads();
    }

    // partial C store: D layout col=lane&15, row=(lane>>4)*4+j
    float* ph = &PH[(unsigned)kz * 1048576u];
#pragma unroll
    for (int m = 0; m < 2; ++m)
#pragma unroll
        for (int n = 0; n < 2; ++n) {
            const int row = z0 + wr * 32 + m * 16 + (lane >> 4) * 4;
            const int col = o0 + wc * 32 + n * 16 + (lane & 15);
#pragma unroll
            for (int j = 0; j < 4; ++j)
                ph[(row + j) * 1024 + col] = acc[m][n][j];
        }
}

// ---------------------------------------------------------------------------
// k_out: H = relu(sum of 4 PH slices + bias1); out = H @ fc2_w^T + fc2_b.
// 256 blocks x 256 thr; one wave per z-row (4 rows/block). No atomics.
// ---------------------------------------------------------------------------
__global__ __launch_bounds__(256) void k_out(
    const float* __restrict__ PH, const float* __restrict__ bias1,
    const float* __restrict__ W2, const float* __restrict__ fc2b,
    float* __restrict__ out) {
    __shared__ float W2s[10][1024];            // 40 KB
    const int tid = threadIdx.x;
#pragma unroll
    for (int i = 0; i < 10; ++i) {             // stage all of fc2_w
        const int idx = tid + 256 * i;         // 2560 float4
        ((float4*)W2s)[idx] = ((const float4*)W2)[idx];
    }
    __syncthreads();

    const int wid = tid >> 6, lane = tid & 63;
    const int z = blockIdx.x * 4 + wid;
    float part[10];
#pragma unroll
    for (int j = 0; j < 10; ++j) part[j] = 0.f;
#pragma unroll
    for (int i = 0; i < 16; ++i) {
        const int col = lane + 64 * i;
        float h = PH[z * 1024 + col] + PH[1048576 + z * 1024 + col]
                + PH[2097152 + z * 1024 + col] + PH[3145728 + z * 1024 + col];
        h = fmaxf(h + bias1[col], 0.f);
#pragma unroll
        for (int j = 0; j < 10; ++j) part[j] += h * W2s[j][col];
    }
#pragma unroll
    for (int j = 0; j < 10; ++j) {
#pragma unroll
        for (int off = 32; off > 0; off >>= 1) part[j] += __shfl_xor(part[j], off);
    }
    if (lane == 0) {
#pragma unroll
        for (int j = 0; j < 10; ++j) out[z * 10 + j] = part[j] + fc2b[j];
    }
}

extern "C" void kernel_launch(void* const* d_in, const int* in_sizes, int n_in,
                              void* d_out, int out_size, void* d_ws, size_t ws_size,
                              hipStream_t stream) {
    const float* x     = (const float*)d_in[0];
    const float* u1    = (const float*)d_in[1];
    const float* u2    = (const float*)d_in[2];
    const float* u3    = (const float*)d_in[3];
    const float* b2    = (const float*)d_in[4];
    const float* b1c   = (const float*)d_in[5];
    const float* bias1 = (const float*)d_in[6];
    const float* fc2w  = (const float*)d_in[7];
    const float* fc2b  = (const float*)d_in[8];
    float* out = (float*)d_out;

    short* Wb = (short*)d_ws;                                  // 2 MB bf16
    short* Xb = (short*)((char*)d_ws + 2u * 1024u * 1024u);    // 2 MB bf16
    float* PH = (float*)((char*)d_ws + 4u * 1024u * 1024u);    // 16 MB f32

    k_prep<<<512, 256, 0, stream>>>(x, u1, u2, u3, b2, b1c, Wb, Xb);
    k_gemm<<<dim3(16, 16, 4), 256, 0, stream>>>(Xb, Wb, PH);
    k_out<<<256, 256, 0, stream>>>(PH, bias1, fc2w, fc2b, out);
}